// Round 10
// baseline (152.259 us; speedup 1.0000x reference)
//
#include <hip/hip_runtime.h>
#include <hip/hip_bf16.h>
#include <math.h>

#define DD 32
#define HH 128

typedef __attribute__((ext_vector_type(8))) __bf16 bf16x8;
typedef __attribute__((ext_vector_type(4))) float  f32x4;
typedef __attribute__((ext_vector_type(2))) int    i32x2;

// ---- ws layout (float offsets) -------------------------------------------
// [0,192)          tripg : 6 x 32 raw triple gradients
// [192,200)        tripS : 6 src row indices (int view)
// [256,33024)      wtab  : 4 s x 64 lanes x 128-float records (128 KB)
// [33024,+npart)   partner
#define WS_TRIPG 0
#define WS_TRIPS 192
#define WS_WTAB  256
#define WS_PART  33024

// record layout (float offsets within a (s,lane) 128-float record):
//  0:W1H(2s) 4:W1L(2s) 8:W1H(2s+1) 12:W1L(2s+1)
// 16:W2H(nt0,s) 20:W2L(nt0,s) 24:W2H(nt1,s) 28:W2L(nt1,s)
// 32:P1H(2s) 36:P1L(2s) 40:P1H(2s+1) 44:P1L(2s+1)
// 48:PTH(nt0,s) 52:PTL(nt0,s) 56:PTH(nt1,s) 60:PTL(nt1,s)
// 64:c0 pair0  68:c0 pair1  72:pb1 pair0 76:pb1 pair1  80:pW2 p0 84:pW2 p1

#define ENC_ZF  0x40000000u
#define ENC_SEC 0x80000000u

union b8u { bf16x8 v; uint32_t u[4]; };

__device__ __forceinline__ f32x4 mfma16(bf16x8 a, bf16x8 b, f32x4 c) {
    return __builtin_amdgcn_mfma_f32_16x16x32_bf16(a, b, c, 0, 0, 0);
}

// split (a,b) into packed-bf16 hi word and lo word (RNE, == scalar casts)
__device__ __forceinline__ void split2(float a, float b,
                                       uint32_t& h, uint32_t& l) {
    __hip_bfloat162 hb = __float22bfloat162_rn(make_float2(a, b));
    uint32_t hu; __builtin_memcpy(&hu, &hb, 4);
    float af = __uint_as_float(hu << 16);
    float bf = __uint_as_float(hu & 0xffff0000u);
    __hip_bfloat162 lb = __float22bfloat162_rn(make_float2(a - af, b - bf));
    uint32_t lu; __builtin_memcpy(&lu, &lb, 4);
    h = hu; l = lu;
}

// tanh(x) = 1 - 2/(e^{2x}+1)  (overflow-safe, no fabs/copysign)
__device__ __forceinline__ float tanh_fast(float x) {
    float e = __expf(2.0f * x);
    float q = __fdividef(2.0f, e + 1.0f);
    return 1.0f - q;
}
// w * sech^2(x) = w * q*(2-q), q = 2/(e^{2x}+1)   [= w*(1-t^2)]
__device__ __forceinline__ float wsech2(float w, float x) {
    float e = __expf(2.0f * x);
    float q = __fdividef(2.0f, e + 1.0f);
    return w * (q * (2.0f - q));
}

// ---- Prep 1: packed per-(s,lane) weight records ---------------------------
// kappa conventions (A and B share kappa -> correct for any hw k-order):
//   GEMM1 (K=32):  kappa1(g,i) = 8g + i
//   GEMM2 (K=128, step s): kappa2(g,s,i) = 16*(2s + (i>>2)) + 4g + (i&3)
__global__ void k_prep(const float* __restrict__ t,
                       const float* __restrict__ vW1,  // (33,128)
                       const float* __restrict__ vb1,  // (128)
                       const float* __restrict__ vW2,  // (128,32)
                       const float* __restrict__ pW1,  // (32,128)
                       const float* __restrict__ pb1,  // (128)
                       const float* __restrict__ pW2,  // (128)
                       float* __restrict__ ws)
{
    int tid = blockIdx.x * 256 + threadIdx.x;
    int b = tid >> 6, lane = tid & 63;
    int g = lane >> 4, m = lane & 15;
    if (b < 32) {
        int s = b >> 3, slot = b & 7;
        float v[8];
        int off;
        if (slot < 2) {                       // W1-A (vW1), th = 2s+slot
            int th = 2 * s + slot;
            #pragma unroll
            for (int i = 0; i < 8; i++)
                v[i] = vW1[(8 * g + i) * HH + 16 * th + m];
            off = slot * 8;
        } else if (slot < 4) {                // W2-B, nt = slot-2
            int nt = slot - 2;
            #pragma unroll
            for (int i = 0; i < 8; i++) {
                int kh = 16 * (2 * s + (i >> 2)) + 4 * g + (i & 3);
                v[i] = vW2[kh * DD + nt * 16 + m];
            }
            off = 16 + nt * 8;
        } else if (slot < 6) {                // P1-A (pW1), th = 2s+(slot-4)
            int th = 2 * s + (slot - 4);
            #pragma unroll
            for (int i = 0; i < 8; i++)
                v[i] = pW1[(8 * g + i) * HH + 16 * th + m];
            off = 32 + (slot - 4) * 8;
        } else {                              // PT-B (pW1^T), nt = slot-6
            int nt = slot - 6;
            #pragma unroll
            for (int i = 0; i < 8; i++) {
                int kh = 16 * (2 * s + (i >> 2)) + 4 * g + (i & 3);
                v[i] = pW1[(nt * 16 + m) * HH + kh];
            }
            off = 48 + nt * 8;
        }
        b8u H, L;
        #pragma unroll
        for (int j = 0; j < 4; j++)
            split2(v[2 * j], v[2 * j + 1], H.u[j], L.u[j]);
        float* rec = ws + WS_WTAB + (size_t)(s * 64 + lane) * 128;
        *(f32x4*)(rec + off)     = *(f32x4*)&H;
        *(f32x4*)(rec + off + 4) = *(f32x4*)&L;
    } else if (b < 36) {
        int s = b - 32;
        float* rec = ws + WS_WTAB + (size_t)(s * 64 + lane) * 128;
        float tv = t[0];
        #pragma unroll
        for (int p = 0; p < 2; p++) {
            int th = 2 * s + p;
            #pragma unroll
            for (int j = 0; j < 4; j++) {
                int kh = 16 * th + 4 * g + j;
                rec[64 + p * 4 + j] = vb1[kh] + tv * vW1[DD * HH + kh];
                rec[72 + p * 4 + j] = pb1[kh];
                rec[80 + p * 4 + j] = pW2[kh];
            }
        }
    }
}

// ---- Prep 2: row-centric partner[] ----------------------------------------
__global__ void k_prep2(const int* __restrict__ perm,
                        unsigned int* __restrict__ partner,
                        int* __restrict__ tripS,
                        int np, int ntr, int B, int npart)
{
    int j = blockIdx.x * 256 + threadIdx.x;
    if (j < np) {
        int a = perm[2 * j], b = perm[2 * j + 1];
        partner[a] = (unsigned int)b;
        partner[b] = (unsigned int)a | ENC_SEC;
    }
    if (j == 0) {
        int base = B;
        if (ntr) {
            for (int i = 0; i < 3; i++)
                partner[perm[2 * np + i]] = ENC_ZF;
            for (int ti = 0; ti < 6; ti++) {
                int i3 = ti >> 1, r3 = ti & 1;
                int j3 = r3 + ((r3 >= i3) ? 1 : 0);
                tripS[ti] = perm[2 * np + i3];
                partner[B + ti] = (unsigned int)perm[2 * np + j3];
            }
            base = B + 6;
        }
        for (int q = base; q < npart; q++) partner[q] = ENC_ZF;
    }
}

// ---- Main: out[i] = dzdt(z_i) + fs_i * grad_phi(d_i) ----------------------
__global__ __launch_bounds__(256) void k_main(
    const float* __restrict__ z,
    const float* __restrict__ ws,
    const unsigned int* __restrict__ partner,
    const float* __restrict__ vb2,
    float* __restrict__ out,
    float* __restrict__ tripg,
    int B, int ntiles)
{
    int lane = threadIdx.x & 63;
    int tt   = blockIdx.x * 4 + (threadIdx.x >> 6);
    if (tt >= ntiles) return;
    int g = lane >> 4, m = lane & 15;
    const int* tripS = (const int*)(ws + WS_TRIPS);

    int rbase = tt * 16;
    int ilog  = rbase + m;

    unsigned int enc = partner[ilog];
    int  pi  = (int)(enc & 0x3FFFFFFFu);
    bool zf  = (enc & ENC_ZF) != 0;
    bool sec = (enc & ENC_SEC) != 0;
    float fs = zf ? 0.f : (sec ? 1.f : -1.f);

    int isrc = ilog;
    if (ilog >= B) {
        int ti = ilog - B;
        isrc = (ti < 6) ? tripS[ti] : 0;
    }

    const float* pz = z + (size_t)isrc * DD + 8 * g;
    const float* pp = z + (size_t)pi   * DD + 8 * g;
    f32x4 zi0 = *(const f32x4*)pz, zi1 = *(const f32x4*)(pz + 4);
    f32x4 zp0 = *(const f32x4*)pp, zp1 = *(const f32x4*)(pp + 4);
    float vb20 = vb2[m], vb21 = vb2[16 + m];

    b8u ZH, ZL, DH, DL;
    split2(zi0[0], zi0[1], ZH.u[0], ZL.u[0]);
    split2(zi0[2], zi0[3], ZH.u[1], ZL.u[1]);
    split2(zi1[0], zi1[1], ZH.u[2], ZL.u[2]);
    split2(zi1[2], zi1[3], ZH.u[3], ZL.u[3]);
    {
        float d0 = -fs * (zi0[0] - zp0[0]), d1 = -fs * (zi0[1] - zp0[1]);
        float d2 = -fs * (zi0[2] - zp0[2]), d3 = -fs * (zi0[3] - zp0[3]);
        float d4 = -fs * (zi1[0] - zp1[0]), d5 = -fs * (zi1[1] - zp1[1]);
        float d6 = -fs * (zi1[2] - zp1[2]), d7 = -fs * (zi1[3] - zp1[3]);
        split2(d0, d1, DH.u[0], DL.u[0]);
        split2(d2, d3, DH.u[1], DL.u[1]);
        split2(d4, d5, DH.u[2], DL.u[2]);
        split2(d6, d7, DH.u[3], DL.u[3]);
    }

    // ---- net1: dz_dt -------------------------------------------------------
    f32x4 accv0 = (f32x4){vb20, vb20, vb20, vb20};
    f32x4 accv1 = (f32x4){vb21, vb21, vb21, vb21};
    {
        const float* wb = ws + WS_WTAB + (size_t)lane * 128;
        #pragma unroll 1
        for (int s = 0; s < 4; s++, wb += 64 * 128) {
            bf16x8 w1h0 = *(const bf16x8*)(wb + 0);
            bf16x8 w1l0 = *(const bf16x8*)(wb + 4);
            bf16x8 w1h1 = *(const bf16x8*)(wb + 8);
            bf16x8 w1l1 = *(const bf16x8*)(wb + 12);
            f32x4 u0 = *(const f32x4*)(wb + 64);
            f32x4 u1 = *(const f32x4*)(wb + 68);
            u0 = mfma16(w1h0, ZL.v, u0); u0 = mfma16(w1l0, ZH.v, u0); u0 = mfma16(w1h0, ZH.v, u0);
            u1 = mfma16(w1h1, ZL.v, u1); u1 = mfma16(w1l1, ZH.v, u1); u1 = mfma16(w1h1, ZH.v, u1);
            float t0 = tanh_fast(u0[0]), t1 = tanh_fast(u0[1]);
            float t2 = tanh_fast(u0[2]), t3 = tanh_fast(u0[3]);
            float t4 = tanh_fast(u1[0]), t5 = tanh_fast(u1[1]);
            float t6 = tanh_fast(u1[2]), t7 = tanh_fast(u1[3]);
            b8u AH, AL;
            split2(t0, t1, AH.u[0], AL.u[0]);
            split2(t2, t3, AH.u[1], AL.u[1]);
            split2(t4, t5, AH.u[2], AL.u[2]);
            split2(t6, t7, AH.u[3], AL.u[3]);
            bf16x8 b0h = *(const bf16x8*)(wb + 16);
            bf16x8 b0l = *(const bf16x8*)(wb + 20);
            bf16x8 b1h = *(const bf16x8*)(wb + 24);
            bf16x8 b1l = *(const bf16x8*)(wb + 28);
            accv0 = mfma16(AH.v, b0l, accv0); accv0 = mfma16(AL.v, b0h, accv0); accv0 = mfma16(AH.v, b0h, accv0);
            accv1 = mfma16(AH.v, b1l, accv1); accv1 = mfma16(AL.v, b1h, accv1); accv1 = mfma16(AH.v, b1h, accv1);
        }
    }

    // ---- net2: grad_phi ----------------------------------------------------
    f32x4 accf0 = (f32x4){0.f, 0.f, 0.f, 0.f}, accf1 = accf0;
    {
        const float* wb = ws + WS_WTAB + (size_t)lane * 128;
        #pragma unroll 1
        for (int s = 0; s < 4; s++, wb += 64 * 128) {
            bf16x8 p1h0 = *(const bf16x8*)(wb + 32);
            bf16x8 p1l0 = *(const bf16x8*)(wb + 36);
            bf16x8 p1h1 = *(const bf16x8*)(wb + 40);
            bf16x8 p1l1 = *(const bf16x8*)(wb + 44);
            f32x4 u0 = *(const f32x4*)(wb + 72);
            f32x4 u1 = *(const f32x4*)(wb + 76);
            u0 = mfma16(p1h0, DL.v, u0); u0 = mfma16(p1l0, DH.v, u0); u0 = mfma16(p1h0, DH.v, u0);
            u1 = mfma16(p1h1, DL.v, u1); u1 = mfma16(p1l1, DH.v, u1); u1 = mfma16(p1h1, DH.v, u1);
            f32x4 w2q0 = *(const f32x4*)(wb + 80);
            f32x4 w2q1 = *(const f32x4*)(wb + 84);
            float s0 = wsech2(w2q0[0], u0[0]), s1 = wsech2(w2q0[1], u0[1]);
            float s2 = wsech2(w2q0[2], u0[2]), s3 = wsech2(w2q0[3], u0[3]);
            float s4 = wsech2(w2q1[0], u1[0]), s5 = wsech2(w2q1[1], u1[1]);
            float s6 = wsech2(w2q1[2], u1[2]), s7 = wsech2(w2q1[3], u1[3]);
            b8u AH, AL;
            split2(s0, s1, AH.u[0], AL.u[0]);
            split2(s2, s3, AH.u[1], AL.u[1]);
            split2(s4, s5, AH.u[2], AL.u[2]);
            split2(s6, s7, AH.u[3], AL.u[3]);
            bf16x8 b0h = *(const bf16x8*)(wb + 48);
            bf16x8 b0l = *(const bf16x8*)(wb + 52);
            bf16x8 b1h = *(const bf16x8*)(wb + 56);
            bf16x8 b1l = *(const bf16x8*)(wb + 60);
            accf0 = mfma16(AH.v, b0l, accf0); accf0 = mfma16(AL.v, b0h, accf0); accf0 = mfma16(AH.v, b0h, accf0);
            accf1 = mfma16(AH.v, b1l, accf1); accf1 = mfma16(AL.v, b1h, accf1); accf1 = mfma16(AH.v, b1h, accf1);
        }
    }

    // ---- write -------------------------------------------------------------
    #pragma unroll
    for (int r = 0; r < 4; r++) {
        int rp = rbase + 4 * g + r;
        unsigned int e2 = partner[rp];
        float fsw = (e2 & ENC_ZF) ? 0.f : ((e2 & ENC_SEC) ? 1.f : -1.f);
        if (rp < B) {
            out[(size_t)rp * DD + m]      = accv0[r] + fsw * accf0[r];
            out[(size_t)rp * DD + 16 + m] = accv1[r] + fsw * accf1[r];
        } else {
            int tw = rp - B;
            if (tw < 6) {
                tripg[tw * DD + m]      = accf0[r];
                tripg[tw * DD + 16 + m] = accf1[r];
            }
        }
    }
}

// ---- Triple combine -------------------------------------------------------
__global__ void k_triple_combine(
    const int*   __restrict__ perm,
    const float* __restrict__ tripg,
    float* __restrict__ out,
    int np)
{
    int tid = threadIdx.x;
    if (tid >= 3 * DD) return;
    int i = tid >> 5, d = tid & (DD - 1);
    int row = perm[2 * np + i];
    float s = tripg[(2 * i) * DD + d] + tripg[(2 * i + 1) * DD + d];
    out[(size_t)row * DD + d] -= 2.0f * s;
}

extern "C" void kernel_launch(void* const* d_in, const int* in_sizes, int n_in,
                              void* d_out, int out_size, void* d_ws, size_t ws_size,
                              hipStream_t stream) {
    const float* t    = (const float*)d_in[0];
    const float* z    = (const float*)d_in[1];
    const int*   perm = (const int*)  d_in[2];
    const float* vW1  = (const float*)d_in[3];
    const float* vb1  = (const float*)d_in[4];
    const float* vW2  = (const float*)d_in[5];
    const float* vb2  = (const float*)d_in[6];
    const float* pW1  = (const float*)d_in[7];
    const float* pb1  = (const float*)d_in[8];
    const float* pW2  = (const float*)d_in[9];
    // d_in[10] = pb2: constant, vanishes under grad — unused.

    float* out = (float*)d_out;
    float* ws  = (float*)d_ws;

    int B = in_sizes[2];
    int np, ntr;
    if ((B & 1) == 0) { np = B / 2;       ntr = 0; }
    else              { np = (B - 3) / 2; ntr = 1; }

    int nlog   = B + (ntr ? 6 : 0);
    int ntiles = (nlog + 15) >> 4;
    int npart  = ntiles * 16;

    unsigned int* partner = (unsigned int*)(ws + WS_PART);
    int*          tripS   = (int*)(ws + WS_TRIPS);

    k_prep<<<9, 256, 0, stream>>>(t, vW1, vb1, vW2, pW1, pb1, pW2, ws);
    k_prep2<<<(np + 255) / 256, 256, 0, stream>>>(perm, partner, tripS,
                                                  np, ntr, B, npart);
    k_main<<<(ntiles + 3) / 4, 256, 0, stream>>>(z, ws, partner, vb2,
                                                 out, ws + WS_TRIPG,
                                                 B, ntiles);
    if (ntr) {
        k_triple_combine<<<1, 128, 0, stream>>>(perm, ws + WS_TRIPG, out, np);
    }
}

// Round 11
// 75.221 us; speedup vs baseline: 2.0241x; 2.0241x over previous
//
#include <hip/hip_runtime.h>
#include <hip/hip_bf16.h>
#include <math.h>

#define DD 32
#define HH 128

typedef __attribute__((ext_vector_type(8))) __bf16 bf16x8;
typedef __attribute__((ext_vector_type(4))) float  f32x4;

// ---- ws layout (float offsets) -------------------------------------------
// [0,192)        tripg : 6 x 32 raw triple gradients
// [192,200)      tripS : 6 src row indices (int view)
// [224,352)      c0    : vb1[kh] + t * vW1[32][kh]
// [384,16768)    frags : 64 frags, lane-major (frag*64+lane)*4 floats (64KB)
//                 order: s-blocks of 8 (net1: frags s*8+0..7; net2: 32+s*8+0..7)
//                 within block: [AH(2s) AL(2s) AH(2s+1) AL(2s+1)
//                                BH(nt0) BL(nt0) BH(nt1) BL(nt1)]
// [16768,+npart) partner
#define WS_TRIPG 0
#define WS_TRIPS 192
#define WS_C0    224
#define WS_FRAG  384
#define WS_PART  16768

#define ENC_ZF  0x40000000u
#define ENC_SEC 0x80000000u

union b8u { bf16x8 v; uint32_t u[4]; };

__device__ __forceinline__ f32x4 mfma16(bf16x8 a, bf16x8 b, f32x4 c) {
    return __builtin_amdgcn_mfma_f32_16x16x32_bf16(a, b, c, 0, 0, 0);
}

// split (a,b) into packed-bf16 hi word and lo word (RNE == scalar casts)
__device__ __forceinline__ void split2(float a, float b,
                                       uint32_t& h, uint32_t& l) {
    __hip_bfloat162 hb = __float22bfloat162_rn(make_float2(a, b));
    uint32_t hu; __builtin_memcpy(&hu, &hb, 4);
    float af = __uint_as_float(hu << 16);
    float bf = __uint_as_float(hu & 0xffff0000u);
    __hip_bfloat162 lb = __float22bfloat162_rn(make_float2(a - af, b - bf));
    uint32_t lu; __builtin_memcpy(&lu, &lb, 4);
    h = hu; l = lu;
}

// tanh(x) = 1 - 2/(e^{2x}+1)  (overflow-safe, branch-free)
__device__ __forceinline__ float tanh_fast(float x) {
    float e = __expf(2.0f * x);
    float q = __fdividef(2.0f, e + 1.0f);
    return 1.0f - q;
}
// w*sech^2(x) = w*q*(2-q), q = 2/(e^{2x}+1)
__device__ __forceinline__ float wsech2(float w, float x) {
    float e = __expf(2.0f * x);
    float q = __fdividef(2.0f, e + 1.0f);
    return w * (q * (2.0f - q));
}

// ---- Prep 1: c0 + frag table (lane-major, s-blocked order) ----------------
// kappa conventions (A and B share kappa -> correct for any hw k-order):
//   GEMM1 (K=32):  kappa1(g,i) = 8g + i
//   GEMM2 (K=128, step s): kappa2(g,s,i) = 16*(2s + (i>>2)) + 4g + (i&3)
__global__ void k_prep(const float* __restrict__ t,
                       const float* __restrict__ vW1,  // (33,128)
                       const float* __restrict__ vb1,  // (128)
                       const float* __restrict__ vW2,  // (128,32)
                       const float* __restrict__ pW1,  // (32,128)
                       float* __restrict__ ws)
{
    int tid = blockIdx.x * 256 + threadIdx.x;
    if (tid < 4096) {
        int f = tid >> 6, lane = tid & 63;
        int g = lane >> 4, m = lane & 15;
        int reg  = f >> 5;          // 0:net1  1:net2
        int s    = (f >> 3) & 3;
        int slot = f & 7;
        bool isLo = slot & 1;
        float v[8];
        if (slot < 4) {             // A-operand (vW1 / pW1), th = 2s+(slot>>1)
            const float* W = reg ? pW1 : vW1;
            int th = 2 * s + (slot >> 1);
            #pragma unroll
            for (int i = 0; i < 8; i++)
                v[i] = W[(8 * g + i) * HH + 16 * th + m];
        } else {                    // B-operand, nt = (slot-4)>>1
            int nt = (slot - 4) >> 1;
            #pragma unroll
            for (int i = 0; i < 8; i++) {
                int kh = 16 * (2 * s + (i >> 2)) + 4 * g + (i & 3);
                v[i] = reg ? pW1[(nt * 16 + m) * HH + kh]
                           : vW2[kh * DD + nt * 16 + m];
            }
        }
        b8u H, L;
        #pragma unroll
        for (int j = 0; j < 4; j++)
            split2(v[2 * j], v[2 * j + 1], H.u[j], L.u[j]);
        *(f32x4*)(ws + WS_FRAG + (size_t)(f * 64 + lane) * 4) =
            isLo ? *(f32x4*)&L : *(f32x4*)&H;
    } else if (tid < 4096 + HH) {
        int k = tid - 4096;
        ws[WS_C0 + k] = vb1[k] + t[0] * vW1[DD * HH + k];
    }
}

// ---- Prep 2: row-centric partner[] ----------------------------------------
__global__ void k_prep2(const int* __restrict__ perm,
                        unsigned int* __restrict__ partner,
                        int* __restrict__ tripS,
                        int np, int ntr, int B, int npart)
{
    int j = blockIdx.x * 256 + threadIdx.x;
    if (j < np) {
        int a = perm[2 * j], b = perm[2 * j + 1];
        partner[a] = (unsigned int)b;
        partner[b] = (unsigned int)a | ENC_SEC;
    }
    if (j == 0) {
        int base = B;
        if (ntr) {
            for (int i = 0; i < 3; i++)
                partner[perm[2 * np + i]] = ENC_ZF;
            for (int ti = 0; ti < 6; ti++) {
                int i3 = ti >> 1, r3 = ti & 1;
                int j3 = r3 + ((r3 >= i3) ? 1 : 0);
                tripS[ti] = perm[2 * np + i3];
                partner[B + ti] = (unsigned int)perm[2 * np + j3];
            }
            base = B + 6;
        }
        for (int q = base; q < npart; q++) partner[q] = ENC_ZF;
    }
}

// ---- Main: out[i] = dzdt(z_i) + fs_i * grad_phi(d_i) ----------------------
// 2 tiles/wave with next-tile prefetch (partner+z loads issued before the
// current tile's compute).
__global__ __launch_bounds__(256) void k_main(
    const float* __restrict__ z,
    const float* __restrict__ ws,
    const unsigned int* __restrict__ partner,
    const float* __restrict__ vb2,
    const float* __restrict__ pb1,
    const float* __restrict__ pW2,
    float* __restrict__ out,
    float* __restrict__ tripg,
    int B, int ntiles)
{
    int lane = threadIdx.x & 63;
    int wid  = blockIdx.x * 4 + (threadIdx.x >> 6);
    int nw   = gridDim.x * 4;
    int g = lane >> 4, m = lane & 15;
    const float* fr    = ws + WS_FRAG + (size_t)lane * 4;
    const int*   tripS = (const int*)(ws + WS_TRIPS);

    float vb20 = vb2[m], vb21 = vb2[16 + m];

    auto LOADT = [&](int T, unsigned int& enc,
                     f32x4& zi0, f32x4& zi1, f32x4& zp0, f32x4& zp1) {
        int il = T * 16 + m;
        enc = partner[il];
        int pi = (int)(enc & 0x3FFFFFFFu);
        int isrc = il;
        if (il >= B) { int ti = il - B; isrc = (ti < 6) ? tripS[ti] : 0; }
        const float* pz = z + (size_t)isrc * DD + 8 * g;
        const float* pp = z + (size_t)pi   * DD + 8 * g;
        zi0 = *(const f32x4*)pz; zi1 = *(const f32x4*)(pz + 4);
        zp0 = *(const f32x4*)pp; zp1 = *(const f32x4*)(pp + 4);
    };

    int tt = wid;
    if (tt >= ntiles) return;
    unsigned int ce; f32x4 czi0, czi1, czp0, czp1;
    LOADT(tt, ce, czi0, czi1, czp0, czp1);

    while (true) {
        int tn = tt + nw;
        bool has = (tn < ntiles);
        unsigned int ne; f32x4 nzi0, nzi1, nzp0, nzp1;
        if (has) LOADT(tn, ne, nzi0, nzi1, nzp0, nzp1);   // prefetch

        // ---- conversions ---------------------------------------------------
        bool zf  = (ce & ENC_ZF) != 0;
        bool sec = (ce & ENC_SEC) != 0;
        float fs = zf ? 0.f : (sec ? 1.f : -1.f);
        b8u ZH, ZL, DH, DL;
        split2(czi0[0], czi0[1], ZH.u[0], ZL.u[0]);
        split2(czi0[2], czi0[3], ZH.u[1], ZL.u[1]);
        split2(czi1[0], czi1[1], ZH.u[2], ZL.u[2]);
        split2(czi1[2], czi1[3], ZH.u[3], ZL.u[3]);
        {
            float d0 = -fs * (czi0[0] - czp0[0]), d1 = -fs * (czi0[1] - czp0[1]);
            float d2 = -fs * (czi0[2] - czp0[2]), d3 = -fs * (czi0[3] - czp0[3]);
            float d4 = -fs * (czi1[0] - czp1[0]), d5 = -fs * (czi1[1] - czp1[1]);
            float d6 = -fs * (czi1[2] - czp1[2]), d7 = -fs * (czi1[3] - czp1[3]);
            split2(d0, d1, DH.u[0], DL.u[0]);
            split2(d2, d3, DH.u[1], DL.u[1]);
            split2(d4, d5, DH.u[2], DL.u[2]);
            split2(d6, d7, DH.u[3], DL.u[3]);
        }

        // ---- net1: dz_dt ---------------------------------------------------
        f32x4 accv0 = (f32x4){vb20, vb20, vb20, vb20};
        f32x4 accv1 = (f32x4){vb21, vb21, vb21, vb21};
        {
            const float* wb = fr;                       // net1 frags: s*8+j
            #pragma unroll 1
            for (int s = 0; s < 4; s++, wb += 8 * 256) {
                bf16x8 w1h0 = *(const bf16x8*)(wb + 0 * 256);
                bf16x8 w1l0 = *(const bf16x8*)(wb + 1 * 256);
                bf16x8 w1h1 = *(const bf16x8*)(wb + 2 * 256);
                bf16x8 w1l1 = *(const bf16x8*)(wb + 3 * 256);
                f32x4 u0 = *(const f32x4*)(ws + WS_C0 + 32 * s + 4 * g);
                f32x4 u1 = *(const f32x4*)(ws + WS_C0 + 32 * s + 16 + 4 * g);
                u0 = mfma16(w1h0, ZL.v, u0); u0 = mfma16(w1l0, ZH.v, u0); u0 = mfma16(w1h0, ZH.v, u0);
                u1 = mfma16(w1h1, ZL.v, u1); u1 = mfma16(w1l1, ZH.v, u1); u1 = mfma16(w1h1, ZH.v, u1);
                float t0 = tanh_fast(u0[0]), t1 = tanh_fast(u0[1]);
                float t2 = tanh_fast(u0[2]), t3 = tanh_fast(u0[3]);
                float t4 = tanh_fast(u1[0]), t5 = tanh_fast(u1[1]);
                float t6 = tanh_fast(u1[2]), t7 = tanh_fast(u1[3]);
                b8u AH, AL;
                split2(t0, t1, AH.u[0], AL.u[0]);
                split2(t2, t3, AH.u[1], AL.u[1]);
                split2(t4, t5, AH.u[2], AL.u[2]);
                split2(t6, t7, AH.u[3], AL.u[3]);
                bf16x8 b0h = *(const bf16x8*)(wb + 4 * 256);
                bf16x8 b0l = *(const bf16x8*)(wb + 5 * 256);
                bf16x8 b1h = *(const bf16x8*)(wb + 6 * 256);
                bf16x8 b1l = *(const bf16x8*)(wb + 7 * 256);
                accv0 = mfma16(AH.v, b0l, accv0); accv0 = mfma16(AL.v, b0h, accv0); accv0 = mfma16(AH.v, b0h, accv0);
                accv1 = mfma16(AH.v, b1l, accv1); accv1 = mfma16(AL.v, b1h, accv1); accv1 = mfma16(AH.v, b1h, accv1);
            }
        }

        // ---- net2: grad_phi ------------------------------------------------
        f32x4 accf0 = (f32x4){0.f, 0.f, 0.f, 0.f}, accf1 = accf0;
        {
            const float* wb = fr + 32 * 256;            // net2 frags: 32+s*8+j
            #pragma unroll 1
            for (int s = 0; s < 4; s++, wb += 8 * 256) {
                bf16x8 p1h0 = *(const bf16x8*)(wb + 0 * 256);
                bf16x8 p1l0 = *(const bf16x8*)(wb + 1 * 256);
                bf16x8 p1h1 = *(const bf16x8*)(wb + 2 * 256);
                bf16x8 p1l1 = *(const bf16x8*)(wb + 3 * 256);
                f32x4 u0 = *(const f32x4*)(pb1 + 32 * s + 4 * g);
                f32x4 u1 = *(const f32x4*)(pb1 + 32 * s + 16 + 4 * g);
                u0 = mfma16(p1h0, DL.v, u0); u0 = mfma16(p1l0, DH.v, u0); u0 = mfma16(p1h0, DH.v, u0);
                u1 = mfma16(p1h1, DL.v, u1); u1 = mfma16(p1l1, DH.v, u1); u1 = mfma16(p1h1, DH.v, u1);
                f32x4 w2q0 = *(const f32x4*)(pW2 + 32 * s + 4 * g);
                f32x4 w2q1 = *(const f32x4*)(pW2 + 32 * s + 16 + 4 * g);
                float s0 = wsech2(w2q0[0], u0[0]), s1 = wsech2(w2q0[1], u0[1]);
                float s2 = wsech2(w2q0[2], u0[2]), s3 = wsech2(w2q0[3], u0[3]);
                float s4 = wsech2(w2q1[0], u1[0]), s5 = wsech2(w2q1[1], u1[1]);
                float s6 = wsech2(w2q1[2], u1[2]), s7 = wsech2(w2q1[3], u1[3]);
                b8u AH, AL;
                split2(s0, s1, AH.u[0], AL.u[0]);
                split2(s2, s3, AH.u[1], AL.u[1]);
                split2(s4, s5, AH.u[2], AL.u[2]);
                split2(s6, s7, AH.u[3], AL.u[3]);
                bf16x8 b0h = *(const bf16x8*)(wb + 4 * 256);
                bf16x8 b0l = *(const bf16x8*)(wb + 5 * 256);
                bf16x8 b1h = *(const bf16x8*)(wb + 6 * 256);
                bf16x8 b1l = *(const bf16x8*)(wb + 7 * 256);
                accf0 = mfma16(AH.v, b0l, accf0); accf0 = mfma16(AL.v, b0h, accf0); accf0 = mfma16(AH.v, b0h, accf0);
                accf1 = mfma16(AH.v, b1l, accf1); accf1 = mfma16(AL.v, b1h, accf1); accf1 = mfma16(AH.v, b1h, accf1);
            }
        }

        // ---- write ---------------------------------------------------------
        int rbase = tt * 16;
        #pragma unroll
        for (int r = 0; r < 4; r++) {
            int rp = rbase + 4 * g + r;
            unsigned int e2 = partner[rp];
            float fsw = (e2 & ENC_ZF) ? 0.f : ((e2 & ENC_SEC) ? 1.f : -1.f);
            if (rp < B) {
                out[(size_t)rp * DD + m]      = accv0[r] + fsw * accf0[r];
                out[(size_t)rp * DD + 16 + m] = accv1[r] + fsw * accf1[r];
            } else {
                int tw = rp - B;
                if (tw < 6) {
                    tripg[tw * DD + m]      = accf0[r];
                    tripg[tw * DD + 16 + m] = accf1[r];
                }
            }
        }

        if (!has) break;
        tt = tn; ce = ne;
        czi0 = nzi0; czi1 = nzi1; czp0 = nzp0; czp1 = nzp1;
    }
}

// ---- Triple combine -------------------------------------------------------
__global__ void k_triple_combine(
    const int*   __restrict__ perm,
    const float* __restrict__ tripg,
    float* __restrict__ out,
    int np)
{
    int tid = threadIdx.x;
    if (tid >= 3 * DD) return;
    int i = tid >> 5, d = tid & (DD - 1);
    int row = perm[2 * np + i];
    float s = tripg[(2 * i) * DD + d] + tripg[(2 * i + 1) * DD + d];
    out[(size_t)row * DD + d] -= 2.0f * s;
}

extern "C" void kernel_launch(void* const* d_in, const int* in_sizes, int n_in,
                              void* d_out, int out_size, void* d_ws, size_t ws_size,
                              hipStream_t stream) {
    const float* t    = (const float*)d_in[0];
    const float* z    = (const float*)d_in[1];
    const int*   perm = (const int*)  d_in[2];
    const float* vW1  = (const float*)d_in[3];
    const float* vb1  = (const float*)d_in[4];
    const float* vW2  = (const float*)d_in[5];
    const float* vb2  = (const float*)d_in[6];
    const float* pW1  = (const float*)d_in[7];
    const float* pb1  = (const float*)d_in[8];
    const float* pW2  = (const float*)d_in[9];
    // d_in[10] = pb2: constant, vanishes under grad — unused.

    float* out = (float*)d_out;
    float* ws  = (float*)d_ws;

    int B = in_sizes[2];
    int np, ntr;
    if ((B & 1) == 0) { np = B / 2;       ntr = 0; }
    else              { np = (B - 3) / 2; ntr = 1; }

    int nlog   = B + (ntr ? 6 : 0);
    int ntiles = (nlog + 15) >> 4;
    int npart  = ntiles * 16;

    unsigned int* partner = (unsigned int*)(ws + WS_PART);
    int*          tripS   = (int*)(ws + WS_TRIPS);

    k_prep<<<17, 256, 0, stream>>>(t, vW1, vb1, vW2, pW1, ws);
    k_prep2<<<(np + 255) / 256, 256, 0, stream>>>(perm, partner, tripS,
                                                  np, ntr, B, npart);
    // 2 tiles per wave, prefetch hides the 2nd tile's gather latency
    int grid = (ntiles + 7) >> 3;
    k_main<<<grid, 256, 0, stream>>>(z, ws, partner, vb2, pb1, pW2,
                                     out, ws + WS_TRIPG, B, ntiles);
    if (ntr) {
        k_triple_combine<<<1, 128, 0, stream>>>(perm, ws + WS_TRIPG, out, np);
    }
}

// Round 12
// 59.182 us; speedup vs baseline: 2.5727x; 1.2710x over previous
//
#include <hip/hip_runtime.h>
#include <hip/hip_bf16.h>
#include <math.h>

#define DD 32
#define HH 128

typedef __attribute__((ext_vector_type(8))) __bf16 bf16x8;
typedef __attribute__((ext_vector_type(4))) float  f32x4;

// ---- ws layout (float offsets) -------------------------------------------
// [0,192)        tripg : 6 x 32 raw triple gradients
// [192,200)      tripS : 6 src row indices (int view)
// [224,352)      c0    : vb1[kh] + t * vW1[32][kh]
// [384,16768)    frags : 64 frags, lane-major (frag*64+lane)*4 floats (64KB)
//                 order: s-blocks of 8 (net1: frags s*8+0..7; net2: 32+s*8+0..7)
//                 within block: [AH(2s) AL(2s) AH(2s+1) AL(2s+1)
//                                BH(nt0) BL(nt0) BH(nt1) BL(nt1)]
// [16768,+npart) partner
#define WS_TRIPG 0
#define WS_TRIPS 192
#define WS_C0    224
#define WS_FRAG  384
#define WS_PART  16768

#define ENC_ZF  0x40000000u
#define ENC_SEC 0x80000000u

union b8u { bf16x8 v; uint32_t u[4]; };

__device__ __forceinline__ f32x4 mfma16(bf16x8 a, bf16x8 b, f32x4 c) {
    return __builtin_amdgcn_mfma_f32_16x16x32_bf16(a, b, c, 0, 0, 0);
}

// ---- guaranteed-codegen primitives ---------------------------------------
// packed f32->bf16 RNE: D.lo = cvt(S0), D.hi = cvt(S1)
__device__ __forceinline__ uint32_t cvtpk(float a, float b) {
    uint32_t r;
    asm("v_cvt_pk_bf16_f32 %0, %1, %2" : "=v"(r) : "v"(a), "v"(b));
    return r;
}
__device__ __forceinline__ float vexp2(float x) {   // 2^x
    float r; asm("v_exp_f32 %0, %1" : "=v"(r) : "v"(x)); return r;
}
__device__ __forceinline__ float vrcp(float x) {    // 1/x approx
    float r; asm("v_rcp_f32 %0, %1" : "=v"(r) : "v"(x)); return r;
}

// split (a,b) -> hi word (packed bf16 RNE) + lo word (residual) : 6 insts
__device__ __forceinline__ void split2a(float a, float b,
                                        uint32_t& h, uint32_t& l) {
    h = cvtpk(a, b);
    float af = __uint_as_float(h << 16);
    float bf = __uint_as_float(h & 0xffff0000u);
    l = cvtpk(a - af, b - bf);
}

#define TWO_LOG2E 2.8853900817779268f   // 2*log2(e); e^{2x}=2^{x*TWO_LOG2E}

// tanh(x) = 1 - 2/(e^{2x}+1)
__device__ __forceinline__ float tanh_fast(float x) {
    float e = vexp2(x * TWO_LOG2E);
    float q = 2.0f * vrcp(e + 1.0f);
    return 1.0f - q;
}
// w*sech^2(x) = w*q*(2-q), q = 2/(e^{2x}+1)
__device__ __forceinline__ float wsech2(float w, float x) {
    float e = vexp2(x * TWO_LOG2E);
    float q = 2.0f * vrcp(e + 1.0f);
    return w * (q * (2.0f - q));
}

// split2 for prep (runs once; codegen-cost irrelevant; same RNE semantics)
__device__ __forceinline__ void split2(float a, float b,
                                       uint32_t& h, uint32_t& l) {
    __hip_bfloat162 hb = __float22bfloat162_rn(make_float2(a, b));
    uint32_t hu; __builtin_memcpy(&hu, &hb, 4);
    float af = __uint_as_float(hu << 16);
    float bf = __uint_as_float(hu & 0xffff0000u);
    __hip_bfloat162 lb = __float22bfloat162_rn(make_float2(a - af, b - bf));
    uint32_t lu; __builtin_memcpy(&lu, &lb, 4);
    h = hu; l = lu;
}

// ---- Prep 1: c0 + frag table (lane-major, s-blocked order) ----------------
// kappa conventions (A and B share kappa -> correct for any hw k-order):
//   GEMM1 (K=32):  kappa1(g,i) = 8g + i
//   GEMM2 (K=128, step s): kappa2(g,s,i) = 16*(2s + (i>>2)) + 4g + (i&3)
__global__ void k_prep(const float* __restrict__ t,
                       const float* __restrict__ vW1,  // (33,128)
                       const float* __restrict__ vb1,  // (128)
                       const float* __restrict__ vW2,  // (128,32)
                       const float* __restrict__ pW1,  // (32,128)
                       float* __restrict__ ws)
{
    int tid = blockIdx.x * 256 + threadIdx.x;
    if (tid < 4096) {
        int f = tid >> 6, lane = tid & 63;
        int g = lane >> 4, m = lane & 15;
        int reg  = f >> 5;          // 0:net1  1:net2
        int s    = (f >> 3) & 3;
        int slot = f & 7;
        bool isLo = slot & 1;
        float v[8];
        if (slot < 4) {             // A-operand (vW1 / pW1), th = 2s+(slot>>1)
            const float* W = reg ? pW1 : vW1;
            int th = 2 * s + (slot >> 1);
            #pragma unroll
            for (int i = 0; i < 8; i++)
                v[i] = W[(8 * g + i) * HH + 16 * th + m];
        } else {                    // B-operand, nt = (slot-4)>>1
            int nt = (slot - 4) >> 1;
            #pragma unroll
            for (int i = 0; i < 8; i++) {
                int kh = 16 * (2 * s + (i >> 2)) + 4 * g + (i & 3);
                v[i] = reg ? pW1[(nt * 16 + m) * HH + kh]
                           : vW2[kh * DD + nt * 16 + m];
            }
        }
        b8u H, L;
        #pragma unroll
        for (int j = 0; j < 4; j++)
            split2(v[2 * j], v[2 * j + 1], H.u[j], L.u[j]);
        *(f32x4*)(ws + WS_FRAG + (size_t)(f * 64 + lane) * 4) =
            isLo ? *(f32x4*)&L : *(f32x4*)&H;
    } else if (tid < 4096 + HH) {
        int k = tid - 4096;
        ws[WS_C0 + k] = vb1[k] + t[0] * vW1[DD * HH + k];
    }
}

// ---- Prep 2: row-centric partner[] ----------------------------------------
__global__ void k_prep2(const int* __restrict__ perm,
                        unsigned int* __restrict__ partner,
                        int* __restrict__ tripS,
                        int np, int ntr, int B, int npart)
{
    int j = blockIdx.x * 256 + threadIdx.x;
    if (j < np) {
        int a = perm[2 * j], b = perm[2 * j + 1];
        partner[a] = (unsigned int)b;
        partner[b] = (unsigned int)a | ENC_SEC;
    }
    if (j == 0) {
        int base = B;
        if (ntr) {
            for (int i = 0; i < 3; i++)
                partner[perm[2 * np + i]] = ENC_ZF;
            for (int ti = 0; ti < 6; ti++) {
                int i3 = ti >> 1, r3 = ti & 1;
                int j3 = r3 + ((r3 >= i3) ? 1 : 0);
                tripS[ti] = perm[2 * np + i3];
                partner[B + ti] = (unsigned int)perm[2 * np + j3];
            }
            base = B + 6;
        }
        for (int q = base; q < npart; q++) partner[q] = ENC_ZF;
    }
}

// ---- Main: out[i] = dzdt(z_i) + fs_i * grad_phi(d_i) ----------------------
// One 16-row tile per wave (R9 structure — measured best). All conversions
// via asm cvt_pk; transcendentals via asm v_exp/v_rcp; frag loads from two
// base pointers so offsets fold into the 13-bit immediate.
__global__ __launch_bounds__(256) void k_main(
    const float* __restrict__ z,
    const float* __restrict__ ws,
    const unsigned int* __restrict__ partner,
    const float* __restrict__ vb2,
    const float* __restrict__ pb1,
    const float* __restrict__ pW2,
    float* __restrict__ out,
    float* __restrict__ tripg,
    int B, int ntiles)
{
    int lane = threadIdx.x & 63;
    int tt   = blockIdx.x * 4 + (threadIdx.x >> 6);
    if (tt >= ntiles) return;
    int g = lane >> 4, m = lane & 15;
    const int* tripS = (const int*)(ws + WS_TRIPS);

    int rbase = tt * 16;
    int ilog  = rbase + m;

    unsigned int enc = partner[ilog];
    int pi   = (int)(enc & 0x3FFFFFFFu);
    int isrc = ilog;
    if (ilog >= B) {
        int ti = ilog - B;
        isrc = (ti < 6) ? tripS[ti] : 0;
    }
    float fs = (enc & ENC_ZF) ? 0.f : ((enc & ENC_SEC) ? 1.f : -1.f);

    const float* pz = z + (size_t)isrc * DD + 8 * g;
    const float* pp = z + (size_t)pi   * DD + 8 * g;
    f32x4 zi0 = *(const f32x4*)pz, zi1 = *(const f32x4*)(pz + 4);
    f32x4 zp0 = *(const f32x4*)pp, zp1 = *(const f32x4*)(pp + 4);
    float vb20 = vb2[m], vb21 = vb2[16 + m];

    b8u ZH, ZL, DH, DL;
    split2a(zi0[0], zi0[1], ZH.u[0], ZL.u[0]);
    split2a(zi0[2], zi0[3], ZH.u[1], ZL.u[1]);
    split2a(zi1[0], zi1[1], ZH.u[2], ZL.u[2]);
    split2a(zi1[2], zi1[3], ZH.u[3], ZL.u[3]);
    {
        float d0 = -fs * (zi0[0] - zp0[0]), d1 = -fs * (zi0[1] - zp0[1]);
        float d2 = -fs * (zi0[2] - zp0[2]), d3 = -fs * (zi0[3] - zp0[3]);
        float d4 = -fs * (zi1[0] - zp1[0]), d5 = -fs * (zi1[1] - zp1[1]);
        float d6 = -fs * (zi1[2] - zp1[2]), d7 = -fs * (zi1[3] - zp1[3]);
        split2a(d0, d1, DH.u[0], DL.u[0]);
        split2a(d2, d3, DH.u[1], DL.u[1]);
        split2a(d4, d5, DH.u[2], DL.u[2]);
        split2a(d6, d7, DH.u[3], DL.u[3]);
    }

    // ---- net1: dz_dt -------------------------------------------------------
    f32x4 accv0 = (f32x4){vb20, vb20, vb20, vb20};
    f32x4 accv1 = (f32x4){vb21, vb21, vb21, vb21};
    {
        const float* fa = ws + WS_FRAG + (size_t)lane * 4;  // A frags (slots 0-3)
        const float* fb = fa + 4 * 256;                     // B frags (slots 4-7)
        const float* cg = ws + WS_C0 + 4 * g;
        #pragma unroll 1
        for (int s = 0; s < 4; s++, fa += 8 * 256, fb += 8 * 256) {
            bf16x8 w1h0 = *(const bf16x8*)(fa + 0 * 256);
            bf16x8 w1l0 = *(const bf16x8*)(fa + 1 * 256);
            bf16x8 w1h1 = *(const bf16x8*)(fa + 2 * 256);
            bf16x8 w1l1 = *(const bf16x8*)(fa + 3 * 256);
            f32x4 u0 = *(const f32x4*)(cg + 32 * s);
            f32x4 u1 = *(const f32x4*)(cg + 32 * s + 16);
            u0 = mfma16(w1h0, ZL.v, u0); u0 = mfma16(w1l0, ZH.v, u0); u0 = mfma16(w1h0, ZH.v, u0);
            u1 = mfma16(w1h1, ZL.v, u1); u1 = mfma16(w1l1, ZH.v, u1); u1 = mfma16(w1h1, ZH.v, u1);
            float t0 = tanh_fast(u0[0]), t1 = tanh_fast(u0[1]);
            float t2 = tanh_fast(u0[2]), t3 = tanh_fast(u0[3]);
            float t4 = tanh_fast(u1[0]), t5 = tanh_fast(u1[1]);
            float t6 = tanh_fast(u1[2]), t7 = tanh_fast(u1[3]);
            b8u AH, AL;
            split2a(t0, t1, AH.u[0], AL.u[0]);
            split2a(t2, t3, AH.u[1], AL.u[1]);
            split2a(t4, t5, AH.u[2], AL.u[2]);
            split2a(t6, t7, AH.u[3], AL.u[3]);
            bf16x8 b0h = *(const bf16x8*)(fb + 0 * 256);
            bf16x8 b0l = *(const bf16x8*)(fb + 1 * 256);
            bf16x8 b1h = *(const bf16x8*)(fb + 2 * 256);
            bf16x8 b1l = *(const bf16x8*)(fb + 3 * 256);
            accv0 = mfma16(AH.v, b0l, accv0); accv0 = mfma16(AL.v, b0h, accv0); accv0 = mfma16(AH.v, b0h, accv0);
            accv1 = mfma16(AH.v, b1l, accv1); accv1 = mfma16(AL.v, b1h, accv1); accv1 = mfma16(AH.v, b1h, accv1);
        }
    }

    // ---- net2: grad_phi ----------------------------------------------------
    f32x4 accf0 = (f32x4){0.f, 0.f, 0.f, 0.f}, accf1 = accf0;
    {
        const float* fa = ws + WS_FRAG + (size_t)(32 * 64 + lane) * 4;
        const float* fb = fa + 4 * 256;
        const float* bg = pb1 + 4 * g;
        const float* wg = pW2 + 4 * g;
        #pragma unroll 1
        for (int s = 0; s < 4; s++, fa += 8 * 256, fb += 8 * 256) {
            bf16x8 p1h0 = *(const bf16x8*)(fa + 0 * 256);
            bf16x8 p1l0 = *(const bf16x8*)(fa + 1 * 256);
            bf16x8 p1h1 = *(const bf16x8*)(fa + 2 * 256);
            bf16x8 p1l1 = *(const bf16x8*)(fa + 3 * 256);
            f32x4 u0 = *(const f32x4*)(bg + 32 * s);
            f32x4 u1 = *(const f32x4*)(bg + 32 * s + 16);
            u0 = mfma16(p1h0, DL.v, u0); u0 = mfma16(p1l0, DH.v, u0); u0 = mfma16(p1h0, DH.v, u0);
            u1 = mfma16(p1h1, DL.v, u1); u1 = mfma16(p1l1, DH.v, u1); u1 = mfma16(p1h1, DH.v, u1);
            f32x4 w2q0 = *(const f32x4*)(wg + 32 * s);
            f32x4 w2q1 = *(const f32x4*)(wg + 32 * s + 16);
            float s0 = wsech2(w2q0[0], u0[0]), s1 = wsech2(w2q0[1], u0[1]);
            float s2 = wsech2(w2q0[2], u0[2]), s3 = wsech2(w2q0[3], u0[3]);
            float s4 = wsech2(w2q1[0], u1[0]), s5 = wsech2(w2q1[1], u1[1]);
            float s6 = wsech2(w2q1[2], u1[2]), s7 = wsech2(w2q1[3], u1[3]);
            b8u AH, AL;
            split2a(s0, s1, AH.u[0], AL.u[0]);
            split2a(s2, s3, AH.u[1], AL.u[1]);
            split2a(s4, s5, AH.u[2], AL.u[2]);
            split2a(s6, s7, AH.u[3], AL.u[3]);
            bf16x8 b0h = *(const bf16x8*)(fb + 0 * 256);
            bf16x8 b0l = *(const bf16x8*)(fb + 1 * 256);
            bf16x8 b1h = *(const bf16x8*)(fb + 2 * 256);
            bf16x8 b1l = *(const bf16x8*)(fb + 3 * 256);
            accf0 = mfma16(AH.v, b0l, accf0); accf0 = mfma16(AL.v, b0h, accf0); accf0 = mfma16(AH.v, b0h, accf0);
            accf1 = mfma16(AH.v, b1l, accf1); accf1 = mfma16(AL.v, b1h, accf1); accf1 = mfma16(AH.v, b1h, accf1);
        }
    }

    // ---- write -------------------------------------------------------------
    #pragma unroll
    for (int r = 0; r < 4; r++) {
        int rp = rbase + 4 * g + r;
        unsigned int e2 = partner[rp];
        float fsw = (e2 & ENC_ZF) ? 0.f : ((e2 & ENC_SEC) ? 1.f : -1.f);
        if (rp < B) {
            out[(size_t)rp * DD + m]      = accv0[r] + fsw * accf0[r];
            out[(size_t)rp * DD + 16 + m] = accv1[r] + fsw * accf1[r];
        } else {
            int tw = rp - B;
            if (tw < 6) {
                tripg[tw * DD + m]      = accf0[r];
                tripg[tw * DD + 16 + m] = accf1[r];
            }
        }
    }
}

// ---- Triple combine -------------------------------------------------------
__global__ void k_triple_combine(
    const int*   __restrict__ perm,
    const float* __restrict__ tripg,
    float* __restrict__ out,
    int np)
{
    int tid = threadIdx.x;
    if (tid >= 3 * DD) return;
    int i = tid >> 5, d = tid & (DD - 1);
    int row = perm[2 * np + i];
    float s = tripg[(2 * i) * DD + d] + tripg[(2 * i + 1) * DD + d];
    out[(size_t)row * DD + d] -= 2.0f * s;
}

extern "C" void kernel_launch(void* const* d_in, const int* in_sizes, int n_in,
                              void* d_out, int out_size, void* d_ws, size_t ws_size,
                              hipStream_t stream) {
    const float* t    = (const float*)d_in[0];
    const float* z    = (const float*)d_in[1];
    const int*   perm = (const int*)  d_in[2];
    const float* vW1  = (const float*)d_in[3];
    const float* vb1  = (const float*)d_in[4];
    const float* vW2  = (const float*)d_in[5];
    const float* vb2  = (const float*)d_in[6];
    const float* pW1  = (const float*)d_in[7];
    const float* pb1  = (const float*)d_in[8];
    const float* pW2  = (const float*)d_in[9];
    // d_in[10] = pb2: constant, vanishes under grad — unused.

    float* out = (float*)d_out;
    float* ws  = (float*)d_ws;

    int B = in_sizes[2];
    int np, ntr;
    if ((B & 1) == 0) { np = B / 2;       ntr = 0; }
    else              { np = (B - 3) / 2; ntr = 1; }

    int nlog   = B + (ntr ? 6 : 0);
    int ntiles = (nlog + 15) >> 4;
    int npart  = ntiles * 16;

    unsigned int* partner = (unsigned int*)(ws + WS_PART);
    int*          tripS   = (int*)(ws + WS_TRIPS);

    k_prep<<<17, 256, 0, stream>>>(t, vW1, vb1, vW2, pW1, ws);
    k_prep2<<<(np + 255) / 256, 256, 0, stream>>>(perm, partner, tripS,
                                                  np, ntr, B, npart);
    // one 16-row tile per wave
    k_main<<<(ntiles + 3) / 4, 256, 0, stream>>>(z, ws, partner, vb2, pb1,
                                                 pW2, out, ws + WS_TRIPG,
                                                 B, ntiles);
    if (ntr) {
        k_triple_combine<<<1, 128, 0, stream>>>(perm, ws + WS_TRIPG, out, np);
    }
}

// Round 14
// 53.920 us; speedup vs baseline: 2.8238x; 1.0976x over previous
//
#include <hip/hip_runtime.h>
#include <hip/hip_bf16.h>
#include <math.h>

#define DD 32
#define HH 128

typedef __attribute__((ext_vector_type(8))) __bf16 bf16x8;
typedef __attribute__((ext_vector_type(4))) float  f32x4;

// ---- ws layout (float offsets) -------------------------------------------
// [0,192)        tripg : 6 x 32 raw triple gradients
// [192,200)      tripS : 6 src row indices (int view)
// [224,352)      c0    : vb1[kh] + t * vW1[32][kh]
// [384,16768)    frags : 64 frags, lane-major (frag*64+lane)*4 floats (64KB)
//                 order: s-blocks of 8 (net1: frags s*8+0..7; net2: 32+s*8+0..7)
//                 within block: [AH(2s) AL(2s) AH(2s+1) AL(2s+1)
//                                BH(nt0) BL(nt0) BH(nt1) BL(nt1)]
// [16768,+npart) partner
#define WS_TRIPG 0
#define WS_TRIPS 192
#define WS_C0    224
#define WS_FRAG  384
#define WS_PART  16768

#define ENC_ZF  0x40000000u
#define ENC_SEC 0x80000000u

union b8u { bf16x8 v; uint32_t u[4]; };

__device__ __forceinline__ f32x4 mfma16(bf16x8 a, bf16x8 b, f32x4 c) {
    return __builtin_amdgcn_mfma_f32_16x16x32_bf16(a, b, c, 0, 0, 0);
}

// ---- guaranteed-codegen primitives ---------------------------------------
__device__ __forceinline__ uint32_t cvtpk(float a, float b) {
    uint32_t r;
    asm("v_cvt_pk_bf16_f32 %0, %1, %2" : "=v"(r) : "v"(a), "v"(b));
    return r;
}
__device__ __forceinline__ float vexp2(float x) {   // 2^x
    float r; asm("v_exp_f32 %0, %1" : "=v"(r) : "v"(x)); return r;
}
__device__ __forceinline__ float vrcp(float x) {    // 1/x approx
    float r; asm("v_rcp_f32 %0, %1" : "=v"(r) : "v"(x)); return r;
}

// split (a,b) -> hi word (packed bf16 RNE) + lo word (residual)
__device__ __forceinline__ void split2a(float a, float b,
                                        uint32_t& h, uint32_t& l) {
    h = cvtpk(a, b);
    float af = __uint_as_float(h << 16);
    float bf = __uint_as_float(h & 0xffff0000u);
    l = cvtpk(a - af, b - bf);
}

#define TWO_LOG2E 2.8853900817779268f   // e^{2x} = 2^{x*TWO_LOG2E}

__device__ __forceinline__ float tanh_fast(float x) {   // 1 - 2/(e^{2x}+1)
    float e = vexp2(x * TWO_LOG2E);
    float q = 2.0f * vrcp(e + 1.0f);
    return 1.0f - q;
}
__device__ __forceinline__ float wsech2(float w, float x) { // w*q*(2-q)
    float e = vexp2(x * TWO_LOG2E);
    float q = 2.0f * vrcp(e + 1.0f);
    return w * (q * (2.0f - q));
}

// prep-only split (runs once)
__device__ __forceinline__ void split2(float a, float b,
                                       uint32_t& h, uint32_t& l) {
    __hip_bfloat162 hb = __float22bfloat162_rn(make_float2(a, b));
    uint32_t hu; __builtin_memcpy(&hu, &hb, 4);
    float af = __uint_as_float(hu << 16);
    float bf = __uint_as_float(hu & 0xffff0000u);
    __hip_bfloat162 lb = __float22bfloat162_rn(make_float2(a - af, b - bf));
    uint32_t lu; __builtin_memcpy(&lu, &lb, 4);
    h = hu; l = lu;
}

// ---- Prep 1: c0 + frag table (lane-major, s-blocked order) ----------------
// kappa conventions (A and B share kappa -> correct for any hw k-order):
//   GEMM1 (K=32):  kappa1(g,i) = 8g + i
//   GEMM2 (K=128, step s): kappa2(g,s,i) = 16*(2s + (i>>2)) + 4g + (i&3)
__global__ void k_prep(const float* __restrict__ t,
                       const float* __restrict__ vW1,  // (33,128)
                       const float* __restrict__ vb1,  // (128)
                       const float* __restrict__ vW2,  // (128,32)
                       const float* __restrict__ pW1,  // (32,128)
                       float* __restrict__ ws)
{
    int tid = blockIdx.x * 256 + threadIdx.x;
    if (tid < 4096) {
        int f = tid >> 6, lane = tid & 63;
        int g = lane >> 4, m = lane & 15;
        int reg  = f >> 5;          // 0:net1  1:net2
        int s    = (f >> 3) & 3;
        int slot = f & 7;
        bool isLo = slot & 1;
        float v[8];
        if (slot < 4) {             // A-operand (vW1 / pW1), th = 2s+(slot>>1)
            const float* W = reg ? pW1 : vW1;
            int th = 2 * s + (slot >> 1);
            #pragma unroll
            for (int i = 0; i < 8; i++)
                v[i] = W[(8 * g + i) * HH + 16 * th + m];
        } else {                    // B-operand, nt = (slot-4)>>1
            int nt = (slot - 4) >> 1;
            #pragma unroll
            for (int i = 0; i < 8; i++) {
                int kh = 16 * (2 * s + (i >> 2)) + 4 * g + (i & 3);
                v[i] = reg ? pW1[(nt * 16 + m) * HH + kh]
                           : vW2[kh * DD + nt * 16 + m];
            }
        }
        b8u H, L;
        #pragma unroll
        for (int j = 0; j < 4; j++)
            split2(v[2 * j], v[2 * j + 1], H.u[j], L.u[j]);
        *(f32x4*)(ws + WS_FRAG + (size_t)(f * 64 + lane) * 4) =
            isLo ? *(f32x4*)&L : *(f32x4*)&H;
    } else if (tid < 4096 + HH) {
        int k = tid - 4096;
        ws[WS_C0 + k] = vb1[k] + t[0] * vW1[DD * HH + k];
    }
}

// ---- Prep 2: row-centric partner[] ----------------------------------------
__global__ void k_prep2(const int* __restrict__ perm,
                        unsigned int* __restrict__ partner,
                        int* __restrict__ tripS,
                        int np, int ntr, int B, int npart)
{
    int j = blockIdx.x * 256 + threadIdx.x;
    if (j < np) {
        int a = perm[2 * j], b = perm[2 * j + 1];
        partner[a] = (unsigned int)b;
        partner[b] = (unsigned int)a | ENC_SEC;
    }
    if (j == 0) {
        int base = B;
        if (ntr) {
            for (int i = 0; i < 3; i++)
                partner[perm[2 * np + i]] = ENC_ZF;
            for (int ti = 0; ti < 6; ti++) {
                int i3 = ti >> 1, r3 = ti & 1;
                int j3 = r3 + ((r3 >= i3) ? 1 : 0);
                tripS[ti] = perm[2 * np + i3];
                partner[B + ti] = (unsigned int)perm[2 * np + j3];
            }
            base = B + 6;
        }
        for (int q = base; q < npart; q++) partner[q] = ENC_ZF;
    }
}

// ---- Main: out[i] = dzdt(z_i) + fs_i * grad_phi(d_i) ----------------------
// 32 rows per wave (two 16-row halves) sharing every frag/bias load: halves
// the per-row L2 frag traffic and doubles per-wave independent MFMA work.
// Per-row arithmetic identical to R12 (bitwise same output).
__global__ __launch_bounds__(256) void k_main(
    const float* __restrict__ z,
    const float* __restrict__ ws,
    const unsigned int* __restrict__ partner,
    const float* __restrict__ vb2,
    const float* __restrict__ pb1,
    const float* __restrict__ pW2,
    float* __restrict__ out,
    float* __restrict__ tripg,
    int B, int ntiles)
{
    int lane = threadIdx.x & 63;
    int tt   = blockIdx.x * 4 + (threadIdx.x >> 6);
    if (tt >= ntiles) return;
    int g = lane >> 4, m = lane & 15;
    const int* tripS = (const int*)(ws + WS_TRIPS);

    int rbase = tt * 32;
    int il0 = rbase + m, il1 = rbase + 16 + m;

    unsigned int e0 = partner[il0];
    unsigned int e1 = partner[il1];
    int pi0 = (int)(e0 & 0x3FFFFFFFu);
    int pi1 = (int)(e1 & 0x3FFFFFFFu);
    int is0 = il0, is1 = il1;
    if (il0 >= B) { int ti = il0 - B; is0 = (ti < 6) ? tripS[ti] : 0; }
    if (il1 >= B) { int ti = il1 - B; is1 = (ti < 6) ? tripS[ti] : 0; }
    float fs0 = (e0 & ENC_ZF) ? 0.f : ((e0 & ENC_SEC) ? 1.f : -1.f);
    float fs1 = (e1 & ENC_ZF) ? 0.f : ((e1 & ENC_SEC) ? 1.f : -1.f);

    // issue all 8 z loads up front (2 stream + 2 gather per half)
    const float* pz0 = z + (size_t)is0 * DD + 8 * g;
    const float* pp0 = z + (size_t)pi0 * DD + 8 * g;
    const float* pz1 = z + (size_t)is1 * DD + 8 * g;
    const float* pp1 = z + (size_t)pi1 * DD + 8 * g;
    f32x4 zi00 = *(const f32x4*)pz0, zi01 = *(const f32x4*)(pz0 + 4);
    f32x4 zp00 = *(const f32x4*)pp0, zp01 = *(const f32x4*)(pp0 + 4);
    f32x4 zi10 = *(const f32x4*)pz1, zi11 = *(const f32x4*)(pz1 + 4);
    f32x4 zp10 = *(const f32x4*)pp1, zp11 = *(const f32x4*)(pp1 + 4);
    float vb20 = vb2[m], vb21 = vb2[16 + m];

    b8u Z0H, Z0L, D0H, D0L, Z1H, Z1L, D1H, D1L;
    split2a(zi00[0], zi00[1], Z0H.u[0], Z0L.u[0]);
    split2a(zi00[2], zi00[3], Z0H.u[1], Z0L.u[1]);
    split2a(zi01[0], zi01[1], Z0H.u[2], Z0L.u[2]);
    split2a(zi01[2], zi01[3], Z0H.u[3], Z0L.u[3]);
    split2a(zi10[0], zi10[1], Z1H.u[0], Z1L.u[0]);
    split2a(zi10[2], zi10[3], Z1H.u[1], Z1L.u[1]);
    split2a(zi11[0], zi11[1], Z1H.u[2], Z1L.u[2]);
    split2a(zi11[2], zi11[3], Z1H.u[3], Z1L.u[3]);
    {
        float d0, d1;
        d0 = -fs0 * (zi00[0] - zp00[0]); d1 = -fs0 * (zi00[1] - zp00[1]);
        split2a(d0, d1, D0H.u[0], D0L.u[0]);
        d0 = -fs0 * (zi00[2] - zp00[2]); d1 = -fs0 * (zi00[3] - zp00[3]);
        split2a(d0, d1, D0H.u[1], D0L.u[1]);
        d0 = -fs0 * (zi01[0] - zp01[0]); d1 = -fs0 * (zi01[1] - zp01[1]);
        split2a(d0, d1, D0H.u[2], D0L.u[2]);
        d0 = -fs0 * (zi01[2] - zp01[2]); d1 = -fs0 * (zi01[3] - zp01[3]);
        split2a(d0, d1, D0H.u[3], D0L.u[3]);
        d0 = -fs1 * (zi10[0] - zp10[0]); d1 = -fs1 * (zi10[1] - zp10[1]);
        split2a(d0, d1, D1H.u[0], D1L.u[0]);
        d0 = -fs1 * (zi10[2] - zp10[2]); d1 = -fs1 * (zi10[3] - zp10[3]);
        split2a(d0, d1, D1H.u[1], D1L.u[1]);
        d0 = -fs1 * (zi11[0] - zp11[0]); d1 = -fs1 * (zi11[1] - zp11[1]);
        split2a(d0, d1, D1H.u[2], D1L.u[2]);
        d0 = -fs1 * (zi11[2] - zp11[2]); d1 = -fs1 * (zi11[3] - zp11[3]);
        split2a(d0, d1, D1H.u[3], D1L.u[3]);
    }

    // ---- net1: dz_dt (both halves share frag loads) ------------------------
    f32x4 av00 = (f32x4){vb20, vb20, vb20, vb20};
    f32x4 av01 = (f32x4){vb21, vb21, vb21, vb21};
    f32x4 av10 = av00, av11 = av01;
    {
        const float* fa = ws + WS_FRAG + (size_t)lane * 4;  // A frags
        const float* fb = fa + 4 * 256;                     // B frags
        const float* cg = ws + WS_C0 + 4 * g;
        #pragma unroll 1
        for (int s = 0; s < 4; s++, fa += 8 * 256, fb += 8 * 256) {
            bf16x8 w1h0 = *(const bf16x8*)(fa + 0 * 256);
            bf16x8 w1l0 = *(const bf16x8*)(fa + 1 * 256);
            bf16x8 w1h1 = *(const bf16x8*)(fa + 2 * 256);
            bf16x8 w1l1 = *(const bf16x8*)(fa + 3 * 256);
            f32x4 c0v = *(const f32x4*)(cg + 32 * s);
            f32x4 c1v = *(const f32x4*)(cg + 32 * s + 16);
            f32x4 u00 = c0v, u01 = c1v, u10 = c0v, u11 = c1v;
            u00 = mfma16(w1h0, Z0L.v, u00); u00 = mfma16(w1l0, Z0H.v, u00); u00 = mfma16(w1h0, Z0H.v, u00);
            u01 = mfma16(w1h1, Z0L.v, u01); u01 = mfma16(w1l1, Z0H.v, u01); u01 = mfma16(w1h1, Z0H.v, u01);
            u10 = mfma16(w1h0, Z1L.v, u10); u10 = mfma16(w1l0, Z1H.v, u10); u10 = mfma16(w1h0, Z1H.v, u10);
            u11 = mfma16(w1h1, Z1L.v, u11); u11 = mfma16(w1l1, Z1H.v, u11); u11 = mfma16(w1h1, Z1H.v, u11);
            b8u A0H, A0L, A1H, A1L;
            split2a(tanh_fast(u00[0]), tanh_fast(u00[1]), A0H.u[0], A0L.u[0]);
            split2a(tanh_fast(u00[2]), tanh_fast(u00[3]), A0H.u[1], A0L.u[1]);
            split2a(tanh_fast(u01[0]), tanh_fast(u01[1]), A0H.u[2], A0L.u[2]);
            split2a(tanh_fast(u01[2]), tanh_fast(u01[3]), A0H.u[3], A0L.u[3]);
            split2a(tanh_fast(u10[0]), tanh_fast(u10[1]), A1H.u[0], A1L.u[0]);
            split2a(tanh_fast(u10[2]), tanh_fast(u10[3]), A1H.u[1], A1L.u[1]);
            split2a(tanh_fast(u11[0]), tanh_fast(u11[1]), A1H.u[2], A1L.u[2]);
            split2a(tanh_fast(u11[2]), tanh_fast(u11[3]), A1H.u[3], A1L.u[3]);
            bf16x8 b0h = *(const bf16x8*)(fb + 0 * 256);
            bf16x8 b0l = *(const bf16x8*)(fb + 1 * 256);
            bf16x8 b1h = *(const bf16x8*)(fb + 2 * 256);
            bf16x8 b1l = *(const bf16x8*)(fb + 3 * 256);
            av00 = mfma16(A0H.v, b0l, av00); av00 = mfma16(A0L.v, b0h, av00); av00 = mfma16(A0H.v, b0h, av00);
            av01 = mfma16(A0H.v, b1l, av01); av01 = mfma16(A0L.v, b1h, av01); av01 = mfma16(A0H.v, b1h, av01);
            av10 = mfma16(A1H.v, b0l, av10); av10 = mfma16(A1L.v, b0h, av10); av10 = mfma16(A1H.v, b0h, av10);
            av11 = mfma16(A1H.v, b1l, av11); av11 = mfma16(A1L.v, b1h, av11); av11 = mfma16(A1H.v, b1h, av11);
        }
    }

    // ---- net2: grad_phi ----------------------------------------------------
    f32x4 af00 = (f32x4){0.f, 0.f, 0.f, 0.f};
    f32x4 af01 = af00, af10 = af00, af11 = af00;
    {
        const float* fa = ws + WS_FRAG + (size_t)(32 * 64 + lane) * 4;
        const float* fb = fa + 4 * 256;
        const float* bg = pb1 + 4 * g;
        const float* wg = pW2 + 4 * g;
        #pragma unroll 1
        for (int s = 0; s < 4; s++, fa += 8 * 256, fb += 8 * 256) {
            bf16x8 p1h0 = *(const bf16x8*)(fa + 0 * 256);
            bf16x8 p1l0 = *(const bf16x8*)(fa + 1 * 256);
            bf16x8 p1h1 = *(const bf16x8*)(fa + 2 * 256);
            bf16x8 p1l1 = *(const bf16x8*)(fa + 3 * 256);
            f32x4 c0v = *(const f32x4*)(bg + 32 * s);
            f32x4 c1v = *(const f32x4*)(bg + 32 * s + 16);
            f32x4 u00 = c0v, u01 = c1v, u10 = c0v, u11 = c1v;
            u00 = mfma16(p1h0, D0L.v, u00); u00 = mfma16(p1l0, D0H.v, u00); u00 = mfma16(p1h0, D0H.v, u00);
            u01 = mfma16(p1h1, D0L.v, u01); u01 = mfma16(p1l1, D0H.v, u01); u01 = mfma16(p1h1, D0H.v, u01);
            u10 = mfma16(p1h0, D1L.v, u10); u10 = mfma16(p1l0, D1H.v, u10); u10 = mfma16(p1h0, D1H.v, u10);
            u11 = mfma16(p1h1, D1L.v, u11); u11 = mfma16(p1l1, D1H.v, u11); u11 = mfma16(p1h1, D1H.v, u11);
            f32x4 w2q0 = *(const f32x4*)(wg + 32 * s);
            f32x4 w2q1 = *(const f32x4*)(wg + 32 * s + 16);
            b8u A0H, A0L, A1H, A1L;
            split2a(wsech2(w2q0[0], u00[0]), wsech2(w2q0[1], u00[1]), A0H.u[0], A0L.u[0]);
            split2a(wsech2(w2q0[2], u00[2]), wsech2(w2q0[3], u00[3]), A0H.u[1], A0L.u[1]);
            split2a(wsech2(w2q1[0], u01[0]), wsech2(w2q1[1], u01[1]), A0H.u[2], A0L.u[2]);
            split2a(wsech2(w2q1[2], u01[2]), wsech2(w2q1[3], u01[3]), A0H.u[3], A0L.u[3]);
            split2a(wsech2(w2q0[0], u10[0]), wsech2(w2q0[1], u10[1]), A1H.u[0], A1L.u[0]);
            split2a(wsech2(w2q0[2], u10[2]), wsech2(w2q0[3], u10[3]), A1H.u[1], A1L.u[1]);
            split2a(wsech2(w2q1[0], u11[0]), wsech2(w2q1[1], u11[1]), A1H.u[2], A1L.u[2]);
            split2a(wsech2(w2q1[2], u11[2]), wsech2(w2q1[3], u11[3]), A1H.u[3], A1L.u[3]);
            bf16x8 b0h = *(const bf16x8*)(fb + 0 * 256);
            bf16x8 b0l = *(const bf16x8*)(fb + 1 * 256);
            bf16x8 b1h = *(const bf16x8*)(fb + 2 * 256);
            bf16x8 b1l = *(const bf16x8*)(fb + 3 * 256);
            af00 = mfma16(A0H.v, b0l, af00); af00 = mfma16(A0L.v, b0h, af00); af00 = mfma16(A0H.v, b0h, af00);
            af01 = mfma16(A0H.v, b1l, af01); af01 = mfma16(A0L.v, b1h, af01); af01 = mfma16(A0H.v, b1h, af01);
            af10 = mfma16(A1H.v, b0l, af10); af10 = mfma16(A1L.v, b0h, af10); af10 = mfma16(A1H.v, b0h, af10);
            af11 = mfma16(A1H.v, b1l, af11); af11 = mfma16(A1L.v, b1h, af11); af11 = mfma16(A1H.v, b1h, af11);
        }
    }

    // ---- write both halves -------------------------------------------------
    #pragma unroll
    for (int r = 0; r < 4; r++) {
        int rp = rbase + 4 * g + r;
        unsigned int e2 = partner[rp];
        float fsw = (e2 & ENC_ZF) ? 0.f : ((e2 & ENC_SEC) ? 1.f : -1.f);
        if (rp < B) {
            out[(size_t)rp * DD + m]      = av00[r] + fsw * af00[r];
            out[(size_t)rp * DD + 16 + m] = av01[r] + fsw * af01[r];
        } else {
            int tw = rp - B;
            if (tw < 6) {
                tripg[tw * DD + m]      = af00[r];
                tripg[tw * DD + 16 + m] = af01[r];
            }
        }
        int rq = rbase + 16 + 4 * g + r;
        unsigned int e3 = partner[rq];
        float fsq = (e3 & ENC_ZF) ? 0.f : ((e3 & ENC_SEC) ? 1.f : -1.f);
        if (rq < B) {
            out[(size_t)rq * DD + m]      = av10[r] + fsq * af10[r];
            out[(size_t)rq * DD + 16 + m] = av11[r] + fsq * af11[r];
        } else {
            int tw = rq - B;
            if (tw < 6) {
                tripg[tw * DD + m]      = af10[r];
                tripg[tw * DD + 16 + m] = af11[r];
            }
        }
    }
}

// ---- Triple combine -------------------------------------------------------
__global__ void k_triple_combine(
    const int*   __restrict__ perm,
    const float* __restrict__ tripg,
    float* __restrict__ out,
    int np)
{
    int tid = threadIdx.x;
    if (tid >= 3 * DD) return;
    int i = tid >> 5, d = tid & (DD - 1);
    int row = perm[2 * np + i];
    float s = tripg[(2 * i) * DD + d] + tripg[(2 * i + 1) * DD + d];
    out[(size_t)row * DD + d] -= 2.0f * s;
}

extern "C" void kernel_launch(void* const* d_in, const int* in_sizes, int n_in,
                              void* d_out, int out_size, void* d_ws, size_t ws_size,
                              hipStream_t stream) {
    const float* t    = (const float*)d_in[0];
    const float* z    = (const float*)d_in[1];
    const int*   perm = (const int*)  d_in[2];
    const float* vW1  = (const float*)d_in[3];
    const float* vb1  = (const float*)d_in[4];
    const float* vW2  = (const float*)d_in[5];
    const float* vb2  = (const float*)d_in[6];
    const float* pW1  = (const float*)d_in[7];
    const float* pb1  = (const float*)d_in[8];
    const float* pW2  = (const float*)d_in[9];
    // d_in[10] = pb2: constant, vanishes under grad — unused.

    float* out = (float*)d_out;
    float* ws  = (float*)d_ws;

    int B = in_sizes[2];
    int np, ntr;
    if ((B & 1) == 0) { np = B / 2;       ntr = 0; }
    else              { np = (B - 3) / 2; ntr = 1; }

    int nlog   = B + (ntr ? 6 : 0);
    int ntiles = (nlog + 31) >> 5;           // 32-row tiles
    int npart  = ntiles * 32;

    unsigned int* partner = (unsigned int*)(ws + WS_PART);
    int*          tripS   = (int*)(ws + WS_TRIPS);

    k_prep<<<17, 256, 0, stream>>>(t, vW1, vb1, vW2, pW1, ws);
    k_prep2<<<(np + 255) / 256, 256, 0, stream>>>(perm, partner, tripS,
                                                  np, ntr, B, npart);
    k_main<<<(ntiles + 3) / 4, 256, 0, stream>>>(z, ws, partner, vb2, pb1,
                                                 pW2, out, ws + WS_TRIPG,
                                                 B, ntiles);
    if (ntr) {
        k_triple_combine<<<1, 128, 0, stream>>>(perm, ws + WS_TRIPG, out, np);
    }
}